// Round 3
// baseline (435.453 us; speedup 1.0000x reference)
//
#include <hip/hip_runtime.h>

#define NCH 64
#define SCAN_BLK 1024

// ---------------- CSR build ----------------
// hist: 4 edges per thread, vectorized, independent no-return atomics
__global__ void hist_kernel(const int* __restrict__ dst, int* __restrict__ cnt, int ne) {
    int t = blockIdx.x * blockDim.x + threadIdx.x;
    int e0 = t * 4;
    if (e0 + 4 <= ne) {
        int4 d4 = *(const int4*)(dst + e0);
        atomicAdd(&cnt[d4.x], 1);
        atomicAdd(&cnt[d4.y], 1);
        atomicAdd(&cnt[d4.z], 1);
        atomicAdd(&cnt[d4.w], 1);
    } else {
        for (int e = e0; e < ne; ++e) atomicAdd(&cnt[dst[e]], 1);
    }
}

// per-block exclusive scan; excl gets in-block exclusive prefix, blockSums[b] = block total
__global__ void scan1_kernel(const int* __restrict__ cnt, int* __restrict__ excl,
                             int* __restrict__ blockSums, int n) {
    __shared__ int s[SCAN_BLK];
    int t = threadIdx.x;
    int i = blockIdx.x * SCAN_BLK + t;
    int v = (i < n) ? cnt[i] : 0;
    s[t] = v;
    __syncthreads();
    for (int off = 1; off < SCAN_BLK; off <<= 1) {
        int add = (t >= off) ? s[t - off] : 0;
        __syncthreads();
        s[t] += add;
        __syncthreads();
    }
    if (i < n) excl[i] = s[t] - v;
    if (t == SCAN_BLK - 1) blockSums[blockIdx.x] = s[t];
}

// exclusive scan of block sums (nb <= 128), single block
__global__ void scan2_kernel(int* __restrict__ blockSums, int nb) {
    __shared__ int s[128];
    int t = threadIdx.x;
    s[t] = (t < nb) ? blockSums[t] : 0;
    __syncthreads();
    if (t == 0) {
        int run = 0;
        for (int k = 0; k < nb; ++k) { int v = s[k]; s[k] = run; run += v; }
    }
    __syncthreads();
    if (t < nb) blockSums[t] = s[t];
}

// finalize rowptr, init cursor, compute dinv = rsqrt(1 + indeg)
__global__ void scan3_kernel(const int* __restrict__ cnt, int* __restrict__ rowptr,
                             const int* __restrict__ blockSums, int* __restrict__ cursor,
                             float* __restrict__ dinv, int n, int ne) {
    int i = blockIdx.x * blockDim.x + threadIdx.x;
    if (i >= n) return;
    int rp = rowptr[i] + blockSums[i >> 10];
    rowptr[i] = rp;
    cursor[i] = rp;
    dinv[i] = rsqrtf((float)(cnt[i] + 1));
    if (i == 0) rowptr[n] = ne;
}

// fill: 4 edges per thread; 4 independent atomic-return chains in flight per thread
__global__ void fill_kernel(const int* __restrict__ src, const int* __restrict__ dst,
                            int* __restrict__ cursor, int* __restrict__ csr, int ne) {
    int t = blockIdx.x * blockDim.x + threadIdx.x;
    int e0 = t * 4;
    if (e0 + 4 <= ne) {
        int4 s4 = *(const int4*)(src + e0);
        int4 d4 = *(const int4*)(dst + e0);
        int p0 = atomicAdd(&cursor[d4.x], 1);
        int p1 = atomicAdd(&cursor[d4.y], 1);
        int p2 = atomicAdd(&cursor[d4.z], 1);
        int p3 = atomicAdd(&cursor[d4.w], 1);
        csr[p0] = s4.x;
        csr[p1] = s4.y;
        csr[p2] = s4.z;
        csr[p3] = s4.w;
    } else {
        for (int e = e0; e < ne; ++e) {
            int p = atomicAdd(&cursor[dst[e]], 1);
            csr[p] = src[e];
        }
    }
}

// ---------------- H = dinv[row] * (relu?)(X) @ W ----------------
template<bool RELU>
__global__ void gemm64_kernel(const float* __restrict__ X, const float* __restrict__ W,
                              const float* __restrict__ dinv, float* __restrict__ H, int n) {
    __shared__ float Ws[NCH * NCH];
    int t = threadIdx.x;
    for (int i = t; i < NCH * NCH; i += blockDim.x) Ws[i] = W[i];
    __syncthreads();
    int row = blockIdx.x * blockDim.x + t;
    if (row >= n) return;
    const float4* xr = (const float4*)(X + (long long)row * NCH);
    float acc[NCH];
#pragma unroll
    for (int c = 0; c < NCH; ++c) acc[c] = 0.f;
#pragma unroll
    for (int k4 = 0; k4 < NCH / 4; ++k4) {
        float4 xv = xr[k4];
        if (RELU) {
            xv.x = fmaxf(xv.x, 0.f); xv.y = fmaxf(xv.y, 0.f);
            xv.z = fmaxf(xv.z, 0.f); xv.w = fmaxf(xv.w, 0.f);
        }
        float xs[4] = {xv.x, xv.y, xv.z, xv.w};
#pragma unroll
        for (int j = 0; j < 4; ++j) {
            int k = k4 * 4 + j;
#pragma unroll
            for (int c = 0; c < NCH; ++c)
                acc[c] = fmaf(xs[j], Ws[k * NCH + c], acc[c]);  // uniform LDS read -> broadcast
        }
    }
    float di = dinv[row];
    float4* hr = (float4*)(H + (long long)row * NCH);
#pragma unroll
    for (int c4 = 0; c4 < NCH / 4; ++c4)
        hr[c4] = make_float4(di * acc[4 * c4], di * acc[4 * c4 + 1],
                             di * acc[4 * c4 + 2], di * acc[4 * c4 + 3]);
}

// ---------------- out[d,:] = dinv[d] * (hs[d,:] + sum_{s in N(d)} hs[s,:]) + b ----------------
__global__ void agg_kernel(const float* __restrict__ hs, const int* __restrict__ rowptr,
                           const int* __restrict__ csr, const float* __restrict__ dinv,
                           const float* __restrict__ b, float* __restrict__ out, int n) {
    int wid = (blockIdx.x * blockDim.x + threadIdx.x) >> 6;   // one wave per node
    int lane = threadIdx.x & 63;                              // one lane per channel
    if (wid >= n) return;
    int start = rowptr[wid];
    int end = rowptr[wid + 1];
    float acc = hs[(long long)wid * NCH + lane];              // self-loop term
    int e = start;
    for (; e + 4 <= end; e += 4) {                            // 4 gathers in flight
        int s0 = csr[e], s1 = csr[e + 1], s2 = csr[e + 2], s3 = csr[e + 3];
        float a0 = hs[(long long)s0 * NCH + lane];
        float a1 = hs[(long long)s1 * NCH + lane];
        float a2 = hs[(long long)s2 * NCH + lane];
        float a3 = hs[(long long)s3 * NCH + lane];
        acc += (a0 + a1) + (a2 + a3);
    }
    for (; e < end; ++e) acc += hs[(long long)csr[e] * NCH + lane];
    out[(long long)wid * NCH + lane] = dinv[wid] * acc + b[lane];
}

extern "C" void kernel_launch(void* const* d_in, const int* in_sizes, int n_in,
                              void* d_out, int out_size, void* d_ws, size_t ws_size,
                              hipStream_t stream) {
    const float* x  = (const float*)d_in[0];
    const int*   ei = (const int*)d_in[1];
    const float* W1 = (const float*)d_in[2];
    const float* b1 = (const float*)d_in[3];
    const float* W2 = (const float*)d_in[4];
    const float* b2 = (const float*)d_in[5];
    const int n  = in_sizes[0] / NCH;   // 100000
    const int ne = in_sizes[1] / 2;     // 1600000
    const int* src = ei;
    const int* dst = ei + ne;
    float* out = (float*)d_out;

    // workspace layout (all 256B-aligned)
    char* ws = (char*)d_ws;
    size_t off = 0;
    auto alloc = [&](size_t bytes) { void* p = ws + off; off += (bytes + 255) & ~(size_t)255; return p; };
    int*   cnt       = (int*)alloc((size_t)n * 4);
    int*   rowptr    = (int*)alloc((size_t)(n + 1) * 4);
    int*   cursor    = (int*)alloc((size_t)n * 4);
    int*   blockSums = (int*)alloc(512);
    float* dinv      = (float*)alloc((size_t)n * 4);
    int*   csr       = (int*)alloc((size_t)ne * 4);
    float* bufA      = (float*)alloc((size_t)n * NCH * 4);   // h (scaled)
    // layer-1 aggregated output lives in d_out (overwritten by layer 2 at the end)

    const int blk = 256;
    const int gN  = (n + blk - 1) / blk;
    const int nb  = (n + SCAN_BLK - 1) / SCAN_BLK;           // 98
    const int gAgg = (n * 64 + blk - 1) / blk;               // wave per node
    const int nT4 = (ne + 3) / 4;                            // threads for 4-edge kernels
    const int gE4 = (nT4 + blk - 1) / blk;

    // ---- CSR build (once, reused by both layers) ----
    hipMemsetAsync(cnt, 0, (size_t)n * 4, stream);
    hist_kernel<<<gE4, blk, 0, stream>>>(dst, cnt, ne);
    scan1_kernel<<<nb, SCAN_BLK, 0, stream>>>(cnt, rowptr, blockSums, n);
    scan2_kernel<<<1, 128, 0, stream>>>(blockSums, nb);
    scan3_kernel<<<gN, blk, 0, stream>>>(cnt, rowptr, blockSums, cursor, dinv, n, ne);
    fill_kernel<<<gE4, blk, 0, stream>>>(src, dst, cursor, csr, ne);

    // ---- layer 1 ----
    gemm64_kernel<false><<<gN, blk, 0, stream>>>(x, W1, dinv, bufA, n);
    agg_kernel<<<gAgg, blk, 0, stream>>>(bufA, rowptr, csr, dinv, b1, out, n);

    // ---- layer 2 (relu fused into GEMM load) ----
    gemm64_kernel<true><<<gN, blk, 0, stream>>>(out, W2, dinv, bufA, n);
    agg_kernel<<<gAgg, blk, 0, stream>>>(bufA, rowptr, csr, dinv, b2, out, n);
}

// Round 4
// 277.767 us; speedup vs baseline: 1.5677x; 1.5677x over previous
//
#include <hip/hip_runtime.h>

#define NCH 64
#define NBLK 128          // blocks for coarse hist/scatter
#define CB 512            // coarse bins (dst >> 8)

// ---------------- CSR build: two-level counting sort, LDS atomics only ----------------

// per-block LDS histogram over coarse bins; cntCB[bin*NBLK + blk] = count
__global__ void coarse_hist_kernel(const int* __restrict__ dst, int* __restrict__ cntCB,
                                   int ne, int epb) {
    __shared__ int h[CB];
    int t = threadIdx.x;
    for (int i = t; i < CB; i += blockDim.x) h[i] = 0;
    __syncthreads();
    int e0 = blockIdx.x * epb;
    int e1 = min(e0 + epb, ne);
    for (int e = e0 + t; e < e1; e += blockDim.x)
        atomicAdd(&h[dst[e] >> 8], 1);
    __syncthreads();
    for (int i = t; i < CB; i += blockDim.x) cntCB[i * NBLK + blockIdx.x] = h[i];
}

// one block per coarse bin: exclusive scan of its NBLK counts; binTot[bin] = total
__global__ void binscan_kernel(int* __restrict__ cntCB, int* __restrict__ binTot) {
    __shared__ int s[NBLK];
    int bin = blockIdx.x;
    int t = threadIdx.x;              // NBLK threads
    int v = cntCB[bin * NBLK + t];
    s[t] = v;
    __syncthreads();
    for (int off = 1; off < NBLK; off <<= 1) {
        int add = (t >= off) ? s[t - off] : 0;
        __syncthreads();
        s[t] += add;
        __syncthreads();
    }
    cntCB[bin * NBLK + t] = s[t] - v;               // exclusive within bin
    if (t == NBLK - 1) binTot[bin] = s[t];
}

// single block: exclusive scan of CB bin totals -> cb[]; also rowptr[n] = ne
__global__ void cbscan_kernel(const int* __restrict__ binTot, int* __restrict__ cb,
                              int* __restrict__ rowptr, int n, int ne) {
    __shared__ int s[CB];
    int t = threadIdx.x;              // CB threads
    int v = binTot[t];
    s[t] = v;
    __syncthreads();
    for (int off = 1; off < CB; off <<= 1) {
        int add = (t >= off) ? s[t - off] : 0;
        __syncthreads();
        s[t] += add;
        __syncthreads();
    }
    cb[t] = s[t] - v;                               // exclusive
    if (t == CB - 1) { cb[CB] = ne; rowptr[n] = ne; }
}

// scatter (dst,src) pairs into coarse buckets; per-(bin,block) regions are private
__global__ void coarse_scatter_kernel(const int* __restrict__ src, const int* __restrict__ dst,
                                      const int* __restrict__ cntCB, const int* __restrict__ cb,
                                      int2* __restrict__ coarse, int ne, int epb) {
    __shared__ int cur[CB];
    int t = threadIdx.x;
    for (int i = t; i < CB; i += blockDim.x)
        cur[i] = cb[i] + cntCB[i * NBLK + blockIdx.x];
    __syncthreads();
    int e0 = blockIdx.x * epb;
    int e1 = min(e0 + epb, ne);
    for (int e = e0 + t; e < e1; e += blockDim.x) {
        int d = dst[e];
        int pos = atomicAdd(&cur[d >> 8], 1);       // LDS atomic
        coarse[pos] = make_int2(d, src[e]);
    }
}

// one block per coarse bucket: local counting sort over 256 node bins;
// emits rowptr, dinv, csr
__global__ void bucket_kernel(const int2* __restrict__ coarse, const int* __restrict__ cb,
                              int* __restrict__ rowptr, float* __restrict__ dinv,
                              int* __restrict__ csr, int n) {
    __shared__ int hist[256];
    __shared__ int excl[256];
    __shared__ int cursor[256];
    int k = blockIdx.x;
    int t = threadIdx.x;              // 256 threads
    int base = cb[k];
    int end = cb[k + 1];
    hist[t] = 0;
    __syncthreads();
    for (int i = base + t; i < end; i += 256)
        atomicAdd(&hist[coarse[i].x & 255], 1);
    __syncthreads();
    int v = hist[t];
    excl[t] = v;
    __syncthreads();
    for (int off = 1; off < 256; off <<= 1) {
        int add = (t >= off) ? excl[t - off] : 0;
        __syncthreads();
        excl[t] += add;
        __syncthreads();
    }
    int ex = excl[t] - v;                           // exclusive prefix
    int node = (k << 8) + t;
    if (node < n) {
        rowptr[node] = base + ex;
        dinv[node] = rsqrtf(1.0f + (float)v);
    }
    cursor[t] = base + ex;
    __syncthreads();
    for (int i = base + t; i < end; i += 256) {
        int2 e = coarse[i];
        int pos = atomicAdd(&cursor[e.x & 255], 1); // LDS atomic
        csr[pos] = e.y;
    }
}

// ---------------- H = dinv[row] * (relu?)(X) @ W ----------------
template<bool RELU>
__global__ void gemm64_kernel(const float* __restrict__ X, const float* __restrict__ W,
                              const float* __restrict__ dinv, float* __restrict__ H, int n) {
    __shared__ float Ws[NCH * NCH];
    int t = threadIdx.x;
    for (int i = t; i < NCH * NCH; i += blockDim.x) Ws[i] = W[i];
    __syncthreads();
    int row = blockIdx.x * blockDim.x + t;
    if (row >= n) return;
    const float4* xr = (const float4*)(X + (long long)row * NCH);
    float acc[NCH];
#pragma unroll
    for (int c = 0; c < NCH; ++c) acc[c] = 0.f;
#pragma unroll
    for (int k4 = 0; k4 < NCH / 4; ++k4) {
        float4 xv = xr[k4];
        if (RELU) {
            xv.x = fmaxf(xv.x, 0.f); xv.y = fmaxf(xv.y, 0.f);
            xv.z = fmaxf(xv.z, 0.f); xv.w = fmaxf(xv.w, 0.f);
        }
        float xs[4] = {xv.x, xv.y, xv.z, xv.w};
#pragma unroll
        for (int j = 0; j < 4; ++j) {
            int k = k4 * 4 + j;
#pragma unroll
            for (int c = 0; c < NCH; ++c)
                acc[c] = fmaf(xs[j], Ws[k * NCH + c], acc[c]);  // uniform LDS read -> broadcast
        }
    }
    float di = dinv[row];
    float4* hr = (float4*)(H + (long long)row * NCH);
#pragma unroll
    for (int c4 = 0; c4 < NCH / 4; ++c4)
        hr[c4] = make_float4(di * acc[4 * c4], di * acc[4 * c4 + 1],
                             di * acc[4 * c4 + 2], di * acc[4 * c4 + 3]);
}

// ---------------- out[d,:] = dinv[d] * (hs[d,:] + sum_{s in N(d)} hs[s,:]) + b ----------------
__global__ void agg_kernel(const float* __restrict__ hs, const int* __restrict__ rowptr,
                           const int* __restrict__ csr, const float* __restrict__ dinv,
                           const float* __restrict__ b, float* __restrict__ out, int n) {
    int wid = (blockIdx.x * blockDim.x + threadIdx.x) >> 6;   // one wave per node
    int lane = threadIdx.x & 63;                              // one lane per channel
    if (wid >= n) return;
    int start = rowptr[wid];
    int end = rowptr[wid + 1];
    float acc = hs[(long long)wid * NCH + lane];              // self-loop term
    int e = start;
    for (; e + 4 <= end; e += 4) {                            // 4 gathers in flight
        int s0 = csr[e], s1 = csr[e + 1], s2 = csr[e + 2], s3 = csr[e + 3];
        float a0 = hs[(long long)s0 * NCH + lane];
        float a1 = hs[(long long)s1 * NCH + lane];
        float a2 = hs[(long long)s2 * NCH + lane];
        float a3 = hs[(long long)s3 * NCH + lane];
        acc += (a0 + a1) + (a2 + a3);
    }
    for (; e < end; ++e) acc += hs[(long long)csr[e] * NCH + lane];
    out[(long long)wid * NCH + lane] = dinv[wid] * acc + b[lane];
}

extern "C" void kernel_launch(void* const* d_in, const int* in_sizes, int n_in,
                              void* d_out, int out_size, void* d_ws, size_t ws_size,
                              hipStream_t stream) {
    const float* x  = (const float*)d_in[0];
    const int*   ei = (const int*)d_in[1];
    const float* W1 = (const float*)d_in[2];
    const float* b1 = (const float*)d_in[3];
    const float* W2 = (const float*)d_in[4];
    const float* b2 = (const float*)d_in[5];
    const int n  = in_sizes[0] / NCH;   // 100000
    const int ne = in_sizes[1] / 2;     // 1600000
    const int* src = ei;
    const int* dst = ei + ne;
    float* out = (float*)d_out;

    // workspace layout (all 256B-aligned)
    char* ws = (char*)d_ws;
    size_t off = 0;
    auto alloc = [&](size_t bytes) { void* p = ws + off; off += (bytes + 255) & ~(size_t)255; return p; };
    int*   cntCB   = (int*)alloc((size_t)CB * NBLK * 4);       // 256 KB
    int*   binTot  = (int*)alloc((size_t)CB * 4);
    int*   cb      = (int*)alloc((size_t)(CB + 1) * 4);
    int*   rowptr  = (int*)alloc((size_t)(n + 1) * 4);
    float* dinv    = (float*)alloc((size_t)n * 4);
    int*   csr     = (int*)alloc((size_t)ne * 4);              // 6.4 MB
    int2*  coarse  = (int2*)alloc((size_t)ne * 8);             // 12.8 MB
    float* bufA    = (float*)alloc((size_t)n * NCH * 4);       // 25.6 MB

    const int blk = 256;
    const int gN   = (n + blk - 1) / blk;
    const int gAgg = (n * 64 + blk - 1) / blk;                 // wave per node
    const int epb  = (ne + NBLK - 1) / NBLK;                   // edges per hist/scatter block
    const int nBuck = (n + 255) / 256;                         // 391 used coarse buckets

    // ---- CSR build (no global atomics) ----
    coarse_hist_kernel   <<<NBLK, blk, 0, stream>>>(dst, cntCB, ne, epb);
    binscan_kernel       <<<CB, NBLK, 0, stream>>>(cntCB, binTot);
    cbscan_kernel        <<<1, CB, 0, stream>>>(binTot, cb, rowptr, n, ne);
    coarse_scatter_kernel<<<NBLK, blk, 0, stream>>>(src, dst, cntCB, cb, coarse, ne, epb);
    bucket_kernel        <<<nBuck, 256, 0, stream>>>(coarse, cb, rowptr, dinv, csr, n);

    // ---- layer 1 ----
    gemm64_kernel<false><<<gN, blk, 0, stream>>>(x, W1, dinv, bufA, n);
    agg_kernel<<<gAgg, blk, 0, stream>>>(bufA, rowptr, csr, dinv, b1, out, n);

    // ---- layer 2 (relu fused into GEMM load) ----
    gemm64_kernel<true><<<gN, blk, 0, stream>>>(out, W2, dinv, bufA, n);
    agg_kernel<<<gAgg, blk, 0, stream>>>(bufA, rowptr, csr, dinv, b2, out, n);
}